// Round 4
// baseline (3609.407 us; speedup 1.0000x reference)
//
#include <hip/hip_runtime.h>
#include <math.h>

#define NB 64      // batch
#define NP 12      // encoder steps
#define NQ 12      // decoder steps
#define NT 24      // P+Q
#define NN 325     // nodes
#define ND 64      // units
#define NR 20800   // NN*NB rows
#define CAP 64     // max nnz per S row (mean ~20.5)
#define TSZ 1331200  // NR*ND, one time-slice of Xe

typedef __attribute__((ext_vector_type(8))) short frag8;
typedef __attribute__((ext_vector_type(4))) float f32x4;

__device__ inline unsigned short f2bf(float f) {
  unsigned u = __builtin_bit_cast(unsigned, f);
  unsigned r = u + 0x7FFFu + ((u >> 16) & 1u);
  return (unsigned short)(r >> 16);
}
__device__ inline float bf2f(unsigned short h) {
  unsigned u = ((unsigned)h) << 16;
  return __builtin_bit_cast(float, u);
}
// 8 consecutive fp32 (LDS) -> bf16 hi/lo fragments
__device__ inline void split8(const float* p, frag8& hi, frag8& lo) {
  float4 a = *(const float4*)p, b = *(const float4*)(p + 4);
  float v[8] = {a.x, a.y, a.z, a.w, b.x, b.y, b.z, b.w};
  #pragma unroll
  for (int i = 0; i < 8; i++) {
    unsigned short h = f2bf(v[i]);
    hi[i] = (short)h;
    lo[i] = (short)f2bf(v[i] - bf2f(h));
  }
}

__global__ void k_te(const int* __restrict__ TE, const float* __restrict__ W1,
                     const float* __restrict__ b1, const float* __restrict__ W2,
                     const float* __restrict__ b2, float* __restrict__ te) {
  int row = blockIdx.x;            // b*24+t
  int d = threadIdx.x;
  __shared__ float s[ND];
  int wd = TE[row * 2 + 0], td = TE[row * 2 + 1];
  float v = W1[wd * ND + d] + W1[(7 + td) * ND + d] + b1[d];
  s[d] = v > 0.f ? v : 0.f;
  __syncthreads();
  float acc = b2[d];
  #pragma unroll 8
  for (int k = 0; k < ND; k++) acc = fmaf(s[k], W2[k * ND + d], acc);
  te[row * ND + d] = acc;
}

__global__ void k_zero(float* __restrict__ p, int n) {
  int i = blockIdx.x * 256 + threadIdx.x;
  if (i < n) p[i] = 0.f;
}

// W (384 x nw) fp32 -> k-major bf16 hi/lo: Wh/Wl[n*384 + k]
__global__ void k_convW(const float* __restrict__ W, unsigned short* __restrict__ Wh,
                        unsigned short* __restrict__ Wl, int nw) {
  int k = blockIdx.x;              // 384
  int n = threadIdx.x;             // nw
  float w = W[k * nw + n];
  unsigned short h = f2bf(w);
  Wh[n * 384 + k] = h;
  Wl[n * 384 + k] = f2bf(w - bf2f(h));
}

// CSR build for S0/S1
__global__ void k_csr(const float* __restrict__ S0g, const float* __restrict__ S1g,
                      int* __restrict__ cnt, int* __restrict__ idx,
                      float* __restrict__ val) {
  int m = blockIdx.x, z = blockIdx.y;
  const float* S = z ? S1g : S0g;
  int lane = threadIdx.x;
  int c = 0;
  for (int k0 = 0; k0 < NN; k0 += 64) {
    int k = k0 + lane;
    float v = (k < NN) ? S[m * NN + k] : 0.f;
    bool p = (v != 0.f);
    unsigned long long mask = __ballot(p);
    int pos = c + __popcll(mask & ((1ull << lane) - 1ull));
    if (p) {
      idx[(z * NN + m) * CAP + pos] = k;
      val[(z * NN + m) * CAP + pos] = v;
    }
    c += __popcll(mask);
  }
  if (lane == 0) cnt[z * NN + m] = c;
}

// Precompute x-side input for ALL steps: Xe[t][row][d], row = n*64+b.
// Encoder (t<12): relu(x*Wi1+bi1)@Wi2+bi2 + te + E_se;  decoder: te + E_se.
__global__ void k_xe(const float* __restrict__ X, const float* __restrict__ te,
                     const float* __restrict__ E_se, const float* __restrict__ Wi1,
                     const float* __restrict__ bi1, const float* __restrict__ Wi2,
                     const float* __restrict__ bi2, float* __restrict__ Xe) {
  int row = blockIdx.x, t = blockIdx.y;
  int n = row >> 6, b = row & 63;
  int d = threadIdx.x;
  float acc;
  if (t < NP) {
    __shared__ float s[ND];
    float x = X[(b * NP + t) * NN + n];
    float v = fmaf(x, Wi1[d], bi1[d]);
    s[d] = v > 0.f ? v : 0.f;
    __syncthreads();
    acc = bi2[d];
    #pragma unroll 8
    for (int k = 0; k < ND; k++) acc = fmaf(s[k], Wi2[k * ND + d], acc);
    acc += te[(b * NT + t) * ND + d] + E_se[n * ND + d];
  } else {
    acc = te[(b * NT + t) * ND + d] + E_se[n * ND + d];
  }
  Xe[(size_t)t * TSZ + (size_t)row * ND + d] = acc;
}

// ---------------- Gate kernel (per step) ----------------
// Block (g, m): node m, batch-half g (rows b = g*32 + [0,32)).
// Gathers S@h and S@Xe locally (CSR), runs 6-chunk K=384 bf16x3 MFMA GEMM
// -> sigmoid -> rh, u.  Also computes candX = x-chunks @ Wc (K=192, N=64).
__global__ void __launch_bounds__(256, 2)
k_G(const float* __restrict__ Xe_t, const float* __restrict__ h,
    const int* __restrict__ csrC, const int* __restrict__ csrI,
    const float* __restrict__ csrV,
    const unsigned short* __restrict__ Wgh, const unsigned short* __restrict__ Wgl,
    const float* __restrict__ bg,
    const unsigned short* __restrict__ Wch, const unsigned short* __restrict__ Wcl,
    float* __restrict__ rh, float* __restrict__ u, float* __restrict__ candX) {
  int g = blockIdx.x, m = blockIdx.y;
  int tid = threadIdx.x;
  int lane = tid & 63, w = tid >> 6;
  __shared__ float As[6][32][68];   // chunks: 0=x 1=h 2=S0x 3=S0h 4=S1x 5=S1h
  __shared__ unsigned short Bh[128 * 40], Bl[128 * 40];
  __shared__ unsigned short BCh[64 * 40], BCl[64 * 40];
  __shared__ int sI[2][CAP];
  __shared__ float sV[2][CAP];
  __shared__ int cnt2[2];

  if (tid < 2) cnt2[tid] = csrC[tid * NN + m];
  // stage own rows (x, h)
  int r = tid >> 3, dq = (tid & 7) * 8;
  size_t own = (size_t)(m * 64 + g * 32 + r) * ND + dq;
  {
    float4 xa = *(const float4*)&Xe_t[own], xb = *(const float4*)&Xe_t[own + 4];
    float4 ha = *(const float4*)&h[own],    hb = *(const float4*)&h[own + 4];
    *(float4*)&As[0][r][dq] = xa; *(float4*)&As[0][r][dq + 4] = xb;
    *(float4*)&As[1][r][dq] = ha; *(float4*)&As[1][r][dq + 4] = hb;
  }
  __syncthreads();
  int c0 = cnt2[0], c1 = cnt2[1];
  if (tid < 64) {
    if (tid < c0) { sI[0][tid] = csrI[m * CAP + tid]; sV[0][tid] = csrV[m * CAP + tid]; }
  } else if (tid < 128) {
    int j = tid - 64;
    if (j < c1) { sI[1][j] = csrI[(NN + m) * CAP + j]; sV[1][j] = csrV[(NN + m) * CAP + j]; }
  }
  __syncthreads();
  // gather: each thread owns 8 cols of its row r for all 4 gathered chunks
  int colbase = g * 2048 + r * 64 + dq;
  {
    float ax[8] = {}, ah[8] = {};
    for (int j = 0; j < c0; j++) {
      float v = sV[0][j];
      size_t ka = (size_t)sI[0][j] * 4096 + colbase;
      float4 x0 = *(const float4*)&Xe_t[ka], x1 = *(const float4*)&Xe_t[ka + 4];
      float4 h0 = *(const float4*)&h[ka],    h1 = *(const float4*)&h[ka + 4];
      ax[0] = fmaf(v, x0.x, ax[0]); ax[1] = fmaf(v, x0.y, ax[1]);
      ax[2] = fmaf(v, x0.z, ax[2]); ax[3] = fmaf(v, x0.w, ax[3]);
      ax[4] = fmaf(v, x1.x, ax[4]); ax[5] = fmaf(v, x1.y, ax[5]);
      ax[6] = fmaf(v, x1.z, ax[6]); ax[7] = fmaf(v, x1.w, ax[7]);
      ah[0] = fmaf(v, h0.x, ah[0]); ah[1] = fmaf(v, h0.y, ah[1]);
      ah[2] = fmaf(v, h0.z, ah[2]); ah[3] = fmaf(v, h0.w, ah[3]);
      ah[4] = fmaf(v, h1.x, ah[4]); ah[5] = fmaf(v, h1.y, ah[5]);
      ah[6] = fmaf(v, h1.z, ah[6]); ah[7] = fmaf(v, h1.w, ah[7]);
    }
    #pragma unroll
    for (int i = 0; i < 8; i++) { As[2][r][dq + i] = ax[i]; As[3][r][dq + i] = ah[i]; }
  }
  {
    float ax[8] = {}, ah[8] = {};
    for (int j = 0; j < c1; j++) {
      float v = sV[1][j];
      size_t ka = (size_t)sI[1][j] * 4096 + colbase;
      float4 x0 = *(const float4*)&Xe_t[ka], x1 = *(const float4*)&Xe_t[ka + 4];
      float4 h0 = *(const float4*)&h[ka],    h1 = *(const float4*)&h[ka + 4];
      ax[0] = fmaf(v, x0.x, ax[0]); ax[1] = fmaf(v, x0.y, ax[1]);
      ax[2] = fmaf(v, x0.z, ax[2]); ax[3] = fmaf(v, x0.w, ax[3]);
      ax[4] = fmaf(v, x1.x, ax[4]); ax[5] = fmaf(v, x1.y, ax[5]);
      ax[6] = fmaf(v, x1.z, ax[6]); ax[7] = fmaf(v, x1.w, ax[7]);
      ah[0] = fmaf(v, h0.x, ah[0]); ah[1] = fmaf(v, h0.y, ah[1]);
      ah[2] = fmaf(v, h0.z, ah[2]); ah[3] = fmaf(v, h0.w, ah[3]);
      ah[4] = fmaf(v, h1.x, ah[4]); ah[5] = fmaf(v, h1.y, ah[5]);
      ah[6] = fmaf(v, h1.z, ah[6]); ah[7] = fmaf(v, h1.w, ah[7]);
    }
    #pragma unroll
    for (int i = 0; i < 8; i++) { As[4][r][dq + i] = ax[i]; As[5][r][dq + i] = ah[i]; }
  }

  int rbase = (w & 1) * 16;        // wave row-tile within the 32-row panel
  int cbase = (w >> 1) * 64;       // gate col half (N=128)
  int ccb = (w >> 1) * 32;         // cand col half (N=64)
  int mrow = lane & 15, q = lane >> 4;
  f32x4 accG[4], accC[2];
  #pragma unroll
  for (int i = 0; i < 4; i++) accG[i] = (f32x4)0.f;
  #pragma unroll
  for (int i = 0; i < 2; i++) accC[i] = (f32x4)0.f;

  for (int kt = 0; kt < 12; kt++) {
    int chunk = kt >> 1, kin = (kt & 1) * 32;
    bool isx = ((kt >> 1) & 1) == 0;   // chunks 0,2,4 are x-side
    #pragma unroll
    for (int i = tid; i < 128 * 4; i += 256) {
      int n = i >> 2, qq = (i & 3) * 8;
      *(frag8*)&Bh[n * 40 + qq] = *(const frag8*)&Wgh[n * 384 + kt * 32 + qq];
      *(frag8*)&Bl[n * 40 + qq] = *(const frag8*)&Wgl[n * 384 + kt * 32 + qq];
    }
    if (isx) {
      if (tid < 64 * 4) {
        int n = tid >> 2, qq = (tid & 3) * 8;
        *(frag8*)&BCh[n * 40 + qq] = *(const frag8*)&Wch[n * 384 + kt * 32 + qq];
        *(frag8*)&BCl[n * 40 + qq] = *(const frag8*)&Wcl[n * 384 + kt * 32 + qq];
      }
    }
    __syncthreads();
    frag8 fa_h, fa_l;
    split8(&As[chunk][rbase + mrow][kin + q * 8], fa_h, fa_l);
    #pragma unroll
    for (int ct = 0; ct < 4; ct++) {
      int c = cbase + ct * 16 + mrow;
      frag8 bh = *(const frag8*)&Bh[c * 40 + q * 8];
      frag8 bl = *(const frag8*)&Bl[c * 40 + q * 8];
      accG[ct] = __builtin_amdgcn_mfma_f32_16x16x32_bf16(fa_h, bh, accG[ct], 0, 0, 0);
      accG[ct] = __builtin_amdgcn_mfma_f32_16x16x32_bf16(fa_l, bh, accG[ct], 0, 0, 0);
      accG[ct] = __builtin_amdgcn_mfma_f32_16x16x32_bf16(fa_h, bl, accG[ct], 0, 0, 0);
    }
    if (isx) {
      #pragma unroll
      for (int ct = 0; ct < 2; ct++) {
        int c = ccb + ct * 16 + mrow;
        frag8 bh = *(const frag8*)&BCh[c * 40 + q * 8];
        frag8 bl = *(const frag8*)&BCl[c * 40 + q * 8];
        accC[ct] = __builtin_amdgcn_mfma_f32_16x16x32_bf16(fa_h, bh, accC[ct], 0, 0, 0);
        accC[ct] = __builtin_amdgcn_mfma_f32_16x16x32_bf16(fa_l, bh, accC[ct], 0, 0, 0);
        accC[ct] = __builtin_amdgcn_mfma_f32_16x16x32_bf16(fa_h, bl, accC[ct], 0, 0, 0);
      }
    }
    __syncthreads();
  }
  // epilogue: C/D layout col=lane&15, row=quad*4+reg
  #pragma unroll
  for (int ct = 0; ct < 4; ct++)
    #pragma unroll
    for (int gg = 0; gg < 4; gg++) {
      int rloc = rbase + q * 4 + gg;
      size_t row = (size_t)(m * 64 + g * 32 + rloc);
      int c = cbase + ct * 16 + mrow;
      float v = accG[ct][gg] + bg[c];
      float sg = 1.f / (1.f + __expf(-v));
      if (c < ND) rh[row * ND + c] = sg * As[1][rloc][c];
      else        u[row * ND + (c - ND)] = sg;
    }
  #pragma unroll
  for (int ct = 0; ct < 2; ct++)
    #pragma unroll
    for (int gg = 0; gg < 4; gg++) {
      int rloc = rbase + q * 4 + gg;
      size_t row = (size_t)(m * 64 + g * 32 + rloc);
      int c = ccb + ct * 16 + mrow;
      candX[row * ND + c] = accC[ct][gg];
    }
}

// ---------------- Candidate kernel (per step) ----------------
// Gathers S@rh locally, MFMA over h-side chunks (K=192), adds candX + bias,
// tanh -> GRU update (h in place). DEC: fused output head.
template<int DEC>
__global__ void __launch_bounds__(256, 2)
k_C(const float* __restrict__ rhb, const float* __restrict__ ub,
    const float* __restrict__ candX, float* __restrict__ h,
    const int* __restrict__ csrC, const int* __restrict__ csrI,
    const float* __restrict__ csrV,
    const unsigned short* __restrict__ Wch, const unsigned short* __restrict__ Wcl,
    const float* __restrict__ bc,
    const float* __restrict__ Wo1, const float* __restrict__ bo1,
    const float* __restrict__ Wo2, const float* __restrict__ bo2,
    float* __restrict__ out, int qidx) {
  int g = blockIdx.x, m = blockIdx.y;
  int tid = threadIdx.x;
  int lane = tid & 63, w = tid >> 6;
  __shared__ float As[3][32][68];   // 0=rh 1=S0rh 2=S1rh
  __shared__ float hnewS[32][68];
  __shared__ unsigned short Bh[64 * 40], Bl[64 * 40];
  __shared__ int sI[2][CAP];
  __shared__ float sV[2][CAP];
  __shared__ int cnt2[2];

  if (tid < 2) cnt2[tid] = csrC[tid * NN + m];
  int r = tid >> 3, dq = (tid & 7) * 8;
  size_t own = (size_t)(m * 64 + g * 32 + r) * ND + dq;
  {
    float4 a = *(const float4*)&rhb[own], b = *(const float4*)&rhb[own + 4];
    *(float4*)&As[0][r][dq] = a; *(float4*)&As[0][r][dq + 4] = b;
  }
  __syncthreads();
  int c0 = cnt2[0], c1 = cnt2[1];
  if (tid < 64) {
    if (tid < c0) { sI[0][tid] = csrI[m * CAP + tid]; sV[0][tid] = csrV[m * CAP + tid]; }
  } else if (tid < 128) {
    int j = tid - 64;
    if (j < c1) { sI[1][j] = csrI[(NN + m) * CAP + j]; sV[1][j] = csrV[(NN + m) * CAP + j]; }
  }
  __syncthreads();
  int colbase = g * 2048 + r * 64 + dq;
  #pragma unroll
  for (int z = 0; z < 2; z++) {
    float ac[8] = {};
    int cc = z ? c1 : c0;
    for (int j = 0; j < cc; j++) {
      float v = sV[z][j];
      size_t ka = (size_t)sI[z][j] * 4096 + colbase;
      float4 r0 = *(const float4*)&rhb[ka], r1 = *(const float4*)&rhb[ka + 4];
      ac[0] = fmaf(v, r0.x, ac[0]); ac[1] = fmaf(v, r0.y, ac[1]);
      ac[2] = fmaf(v, r0.z, ac[2]); ac[3] = fmaf(v, r0.w, ac[3]);
      ac[4] = fmaf(v, r1.x, ac[4]); ac[5] = fmaf(v, r1.y, ac[5]);
      ac[6] = fmaf(v, r1.z, ac[6]); ac[7] = fmaf(v, r1.w, ac[7]);
    }
    #pragma unroll
    for (int i = 0; i < 8; i++) As[1 + z][r][dq + i] = ac[i];
  }

  int rbase = (w & 1) * 16;
  int cbase = (w >> 1) * 32;
  int mrow = lane & 15, q = lane >> 4;
  f32x4 acc[2];
  acc[0] = (f32x4)0.f; acc[1] = (f32x4)0.f;

  for (int kt = 0; kt < 6; kt++) {
    int chunk = kt >> 1, kin = (kt & 1) * 32;
    int kglob = 64 + (kt >> 1) * 128 + (kt & 1) * 32;   // h-side rows of Wc
    if (tid < 64 * 4) {
      int n = tid >> 2, qq = (tid & 3) * 8;
      *(frag8*)&Bh[n * 40 + qq] = *(const frag8*)&Wch[n * 384 + kglob + qq];
      *(frag8*)&Bl[n * 40 + qq] = *(const frag8*)&Wcl[n * 384 + kglob + qq];
    }
    __syncthreads();
    frag8 fa_h, fa_l;
    split8(&As[chunk][rbase + mrow][kin + q * 8], fa_h, fa_l);
    #pragma unroll
    for (int ct = 0; ct < 2; ct++) {
      int c = cbase + ct * 16 + mrow;
      frag8 bh = *(const frag8*)&Bh[c * 40 + q * 8];
      frag8 bl = *(const frag8*)&Bl[c * 40 + q * 8];
      acc[ct] = __builtin_amdgcn_mfma_f32_16x16x32_bf16(fa_h, bh, acc[ct], 0, 0, 0);
      acc[ct] = __builtin_amdgcn_mfma_f32_16x16x32_bf16(fa_l, bh, acc[ct], 0, 0, 0);
      acc[ct] = __builtin_amdgcn_mfma_f32_16x16x32_bf16(fa_h, bl, acc[ct], 0, 0, 0);
    }
    __syncthreads();
  }
  #pragma unroll
  for (int ct = 0; ct < 2; ct++)
    #pragma unroll
    for (int gg = 0; gg < 4; gg++) {
      int rloc = rbase + q * 4 + gg;
      size_t row = (size_t)(m * 64 + g * 32 + rloc);
      int c = cbase + ct * 16 + mrow;
      float v = acc[ct][gg] + candX[row * ND + c] + bc[c];
      float cv = tanhf(v);
      float uu = ub[row * ND + c];
      float ho = h[row * ND + c];
      float hn = uu * ho + (1.f - uu) * cv;
      h[row * ND + c] = hn;
      if (DEC) hnewS[rloc][c] = hn;
    }
  if (DEC) {
    __syncthreads();
    int r2 = tid >> 3, d8 = (tid & 7) * 8;
    float s1[8];
    #pragma unroll
    for (int i = 0; i < 8; i++) {
      int d = d8 + i;
      float a = bo1[d];
      #pragma unroll 8
      for (int k = 0; k < ND; k++) a = fmaf(hnewS[r2][k], Wo1[k * ND + d], a);
      s1[i] = a > 0.f ? a : 0.f;
    }
    float p = 0.f;
    #pragma unroll
    for (int i = 0; i < 8; i++) p = fmaf(s1[i], Wo2[d8 + i], p);
    p += __shfl_down(p, 4); p += __shfl_down(p, 2); p += __shfl_down(p, 1);
    if ((tid & 7) == 0)
      out[((size_t)(g * 32 + r2) * NQ + qidx) * NN + m] = p + bo2[0];
  }
}

extern "C" void kernel_launch(void* const* d_in, const int* in_sizes, int n_in,
                              void* d_out, int out_size, void* d_ws, size_t ws_size,
                              hipStream_t stream) {
  const float* X     = (const float*)d_in[0];
  const int*   TE    = (const int*)  d_in[1];
  const float* S0    = (const float*)d_in[2];
  const float* S1    = (const float*)d_in[3];
  const float* W_te1 = (const float*)d_in[4];
  const float* b_te1 = (const float*)d_in[5];
  const float* W_te2 = (const float*)d_in[6];
  const float* b_te2 = (const float*)d_in[7];
  const float* E_se  = (const float*)d_in[8];
  const float* W_in1 = (const float*)d_in[9];
  const float* b_in1 = (const float*)d_in[10];
  const float* W_in2 = (const float*)d_in[11];
  const float* b_in2 = (const float*)d_in[12];
  const float* enc_Wg = (const float*)d_in[13];
  const float* enc_bg = (const float*)d_in[14];
  const float* enc_Wc = (const float*)d_in[15];
  const float* enc_bc = (const float*)d_in[16];
  const float* dec_Wg = (const float*)d_in[17];
  const float* dec_bg = (const float*)d_in[18];
  const float* dec_Wc = (const float*)d_in[19];
  const float* dec_bc = (const float*)d_in[20];
  const float* W_out1 = (const float*)d_in[21];
  const float* b_out1 = (const float*)d_in[22];
  const float* W_out2 = (const float*)d_in[23];
  const float* b_out2 = (const float*)d_in[24];
  float* out = (float*)d_out;
  float* ws = (float*)d_ws;

  // workspace layout (floats); total ~150 MB < 256 MiB
  float* te    = ws;                    // 98304
  float* h     = te + 98304;            // TSZ
  float* rh    = h + TSZ;               // TSZ
  float* u     = rh + TSZ;              // TSZ
  float* candX = u + TSZ;               // TSZ
  float* Xe    = candX + TSZ;           // 24*TSZ
  float* csrV  = Xe + 24 * (size_t)TSZ; // 2*NN*CAP
  int*   csrI  = (int*)(csrV + 2 * NN * CAP);
  int*   csrC  = csrI + 2 * NN * CAP;   // 650, pad to 1024
  unsigned short* wbuf = (unsigned short*)(csrC + 1024);
  unsigned short* egWh = wbuf;                 // 128*384 each
  unsigned short* egWl = egWh + 49152;
  unsigned short* dgWh = egWl + 49152;
  unsigned short* dgWl = dgWh + 49152;
  unsigned short* ecWh = dgWl + 49152;         // 64*384 each
  unsigned short* ecWl = ecWh + 24576;
  unsigned short* dcWh = ecWl + 24576;
  unsigned short* dcWl = dcWh + 24576;

  k_te<<<NB * NT, ND, 0, stream>>>(TE, W_te1, b_te1, W_te2, b_te2, te);
  k_zero<<<(TSZ + 255) / 256, 256, 0, stream>>>(h, TSZ);
  k_csr<<<dim3(NN, 2), 64, 0, stream>>>(S0, S1, csrC, csrI, csrV);
  k_convW<<<384, 128, 0, stream>>>(enc_Wg, egWh, egWl, 128);
  k_convW<<<384, 128, 0, stream>>>(dec_Wg, dgWh, dgWl, 128);
  k_convW<<<384,  64, 0, stream>>>(enc_Wc, ecWh, ecWl, 64);
  k_convW<<<384,  64, 0, stream>>>(dec_Wc, dcWh, dcWl, 64);
  k_xe<<<dim3(NR, NT), ND, 0, stream>>>(X, te, E_se, W_in1, b_in1, W_in2, b_in2, Xe);

  for (int t = 0; t < NT; t++) {
    int enc = (t < NP) ? 1 : 0;
    const unsigned short* Wgh = enc ? egWh : dgWh;
    const unsigned short* Wgl = enc ? egWl : dgWl;
    const unsigned short* Wch = enc ? ecWh : dcWh;
    const unsigned short* Wcl = enc ? ecWl : dcWl;
    const float* bg = enc ? enc_bg : dec_bg;
    const float* bc = enc ? enc_bc : dec_bc;
    const float* Xe_t = Xe + (size_t)t * TSZ;

    k_G<<<dim3(2, NN), 256, 0, stream>>>(Xe_t, h, csrC, csrI, csrV,
                                         Wgh, Wgl, bg, Wch, Wcl, rh, u, candX);
    if (enc)
      k_C<0><<<dim3(2, NN), 256, 0, stream>>>(rh, u, candX, h, csrC, csrI, csrV,
                                              Wch, Wcl, bc, W_out1, b_out1,
                                              W_out2, b_out2, out, 0);
    else
      k_C<1><<<dim3(2, NN), 256, 0, stream>>>(rh, u, candX, h, csrC, csrI, csrV,
                                              Wch, Wcl, bc, W_out1, b_out1,
                                              W_out2, b_out2, out, t - NP);
  }
}

// Round 5
// 2861.158 us; speedup vs baseline: 1.2615x; 1.2615x over previous
//
#include <hip/hip_runtime.h>
#include <math.h>

#define NB 64      // batch
#define NP 12      // encoder steps
#define NQ 12      // decoder steps
#define NT 24      // P+Q
#define NN 325     // nodes
#define ND 64      // units
#define NR 20800   // NN*NB rows
#define CAP 64     // max nnz per S row (mean ~20.5)
#define TSZ 1331200  // NR*ND, one time-slice

typedef __attribute__((ext_vector_type(8))) short frag8;
typedef __attribute__((ext_vector_type(4))) float f32x4;

struct Ptr6 { const float* p[6]; };

__device__ inline unsigned short f2bf(float f) {
  unsigned u = __builtin_bit_cast(unsigned, f);
  unsigned r = u + 0x7FFFu + ((u >> 16) & 1u);
  return (unsigned short)(r >> 16);
}
__device__ inline float bf2f(unsigned short h) {
  unsigned u = ((unsigned)h) << 16;
  return __builtin_bit_cast(float, u);
}

__global__ void k_te(const int* __restrict__ TE, const float* __restrict__ W1,
                     const float* __restrict__ b1, const float* __restrict__ W2,
                     const float* __restrict__ b2, float* __restrict__ te) {
  int row = blockIdx.x;            // b*24+t
  int d = threadIdx.x;
  __shared__ float s[ND];
  int wd = TE[row * 2 + 0], td = TE[row * 2 + 1];
  float v = W1[wd * ND + d] + W1[(7 + td) * ND + d] + b1[d];
  s[d] = v > 0.f ? v : 0.f;
  __syncthreads();
  float acc = b2[d];
  #pragma unroll 8
  for (int k = 0; k < ND; k++) acc = fmaf(s[k], W2[k * ND + d], acc);
  te[row * ND + d] = acc;
}

__global__ void k_zero(float* __restrict__ p, int n) {
  int i = blockIdx.x * 256 + threadIdx.x;
  if (i < n) p[i] = 0.f;
}

// W (384 x nw) fp32 -> k-major bf16 hi/lo: Wh/Wl[n*384 + k]
__global__ void k_convW(const float* __restrict__ W, unsigned short* __restrict__ Wh,
                        unsigned short* __restrict__ Wl, int nw) {
  int k = blockIdx.x;              // 384
  int n = threadIdx.x;             // nw
  float w = W[k * nw + n];
  unsigned short h = f2bf(w);
  Wh[n * 384 + k] = h;
  Wl[n * 384 + k] = f2bf(w - bf2f(h));
}

// CSR build for S0/S1
__global__ void k_csr(const float* __restrict__ S0g, const float* __restrict__ S1g,
                      int* __restrict__ cnt, int* __restrict__ idx,
                      float* __restrict__ val) {
  int m = blockIdx.x, z = blockIdx.y;
  const float* S = z ? S1g : S0g;
  int lane = threadIdx.x;
  int c = 0;
  for (int k0 = 0; k0 < NN; k0 += 64) {
    int k = k0 + lane;
    float v = (k < NN) ? S[m * NN + k] : 0.f;
    bool p = (v != 0.f);
    unsigned long long mask = __ballot(p);
    int pos = c + __popcll(mask & ((1ull << lane) - 1ull));
    if (p) {
      idx[(z * NN + m) * CAP + pos] = k;
      val[(z * NN + m) * CAP + pos] = v;
    }
    c += __popcll(mask);
  }
  if (lane == 0) cnt[z * NN + m] = c;
}

// Precompute x-side input for ALL steps: Xe[t][row][d], row = n*64+b.
// 256 threads = 4 rows per block.
__global__ void k_xe(const float* __restrict__ X, const float* __restrict__ te,
                     const float* __restrict__ E_se, const float* __restrict__ Wi1,
                     const float* __restrict__ bi1, const float* __restrict__ Wi2,
                     const float* __restrict__ bi2, float* __restrict__ Xe) {
  int wv = threadIdx.x >> 6;
  int row = blockIdx.x * 4 + wv;
  int t = blockIdx.y;
  int n = row >> 6, b = row & 63;
  int d = threadIdx.x & 63;
  float acc;
  if (t < NP) {
    __shared__ float s[4][ND];
    float x = X[(b * NP + t) * NN + n];
    float v = fmaf(x, Wi1[d], bi1[d]);
    s[wv][d] = v > 0.f ? v : 0.f;
    __syncthreads();
    acc = bi2[d];
    #pragma unroll 8
    for (int k = 0; k < ND; k++) acc = fmaf(s[wv][k], Wi2[k * ND + d], acc);
    acc += te[(b * NT + t) * ND + d] + E_se[n * ND + d];
  } else {
    acc = te[(b * NT + t) * ND + d] + E_se[n * ND + d];
  }
  Xe[(size_t)t * TSZ + (size_t)row * ND + d] = acc;
}

// Dual gather: for support z and node m, OA[z][m,:] = sum S[m,k]*A[k,:],
// OB[z][m,:] = sum S[m,k]*B[k,:].  C=4096 cols, 1024 per block.
__global__ void k_g2(const float* __restrict__ A, const float* __restrict__ Bsrc,
                     const int* __restrict__ cnt, const int* __restrict__ idx,
                     const float* __restrict__ val,
                     float* __restrict__ OA0, float* __restrict__ OB0,
                     float* __restrict__ OA1, float* __restrict__ OB1) {
  int m = blockIdx.y, z = blockIdx.z;
  int c = blockIdx.x * 1024 + threadIdx.x * 4;
  float* OA = z ? OA1 : OA0;
  float* OB = z ? OB1 : OB0;
  __shared__ int sI[CAP];
  __shared__ float sV[CAP];
  int n = cnt[z * NN + m];
  if ((int)threadIdx.x < n) {
    sI[threadIdx.x] = idx[(z * NN + m) * CAP + threadIdx.x];
    sV[threadIdx.x] = val[(z * NN + m) * CAP + threadIdx.x];
  }
  __syncthreads();
  float4 aa = make_float4(0.f, 0.f, 0.f, 0.f);
  float4 ab = make_float4(0.f, 0.f, 0.f, 0.f);
  for (int j = 0; j < n; j++) {
    float v = sV[j];
    size_t ka = (size_t)sI[j] * 4096 + c;
    float4 x = *(const float4*)&A[ka];
    float4 y = *(const float4*)&Bsrc[ka];
    aa.x = fmaf(v, x.x, aa.x); aa.y = fmaf(v, x.y, aa.y);
    aa.z = fmaf(v, x.z, aa.z); aa.w = fmaf(v, x.w, aa.w);
    ab.x = fmaf(v, y.x, ab.x); ab.y = fmaf(v, y.y, ab.y);
    ab.z = fmaf(v, y.z, ab.z); ab.w = fmaf(v, y.w, ab.w);
  }
  *(float4*)&OA[(size_t)m * 4096 + c] = aa;
  *(float4*)&OB[(size_t)m * 4096 + c] = ab;
}

// Single gather (rh)
__global__ void k_g1(const float* __restrict__ A, const int* __restrict__ cnt,
                     const int* __restrict__ idx, const float* __restrict__ val,
                     float* __restrict__ O0, float* __restrict__ O1) {
  int m = blockIdx.y, z = blockIdx.z;
  int c = blockIdx.x * 1024 + threadIdx.x * 4;
  float* O = z ? O1 : O0;
  __shared__ int sI[CAP];
  __shared__ float sV[CAP];
  int n = cnt[z * NN + m];
  if ((int)threadIdx.x < n) {
    sI[threadIdx.x] = idx[(z * NN + m) * CAP + threadIdx.x];
    sV[threadIdx.x] = val[(z * NN + m) * CAP + threadIdx.x];
  }
  __syncthreads();
  float4 aa = make_float4(0.f, 0.f, 0.f, 0.f);
  int j = 0;
  for (; j + 2 <= n; j += 2) {
    float v0 = sV[j], v1 = sV[j + 1];
    float4 x0 = *(const float4*)&A[(size_t)sI[j] * 4096 + c];
    float4 x1 = *(const float4*)&A[(size_t)sI[j + 1] * 4096 + c];
    aa.x = fmaf(v0, x0.x, aa.x); aa.y = fmaf(v0, x0.y, aa.y);
    aa.z = fmaf(v0, x0.z, aa.z); aa.w = fmaf(v0, x0.w, aa.w);
    aa.x = fmaf(v1, x1.x, aa.x); aa.y = fmaf(v1, x1.y, aa.y);
    aa.z = fmaf(v1, x1.z, aa.z); aa.w = fmaf(v1, x1.w, aa.w);
  }
  if (j < n) {
    float v0 = sV[j];
    float4 x0 = *(const float4*)&A[(size_t)sI[j] * 4096 + c];
    aa.x = fmaf(v0, x0.x, aa.x); aa.y = fmaf(v0, x0.y, aa.y);
    aa.z = fmaf(v0, x0.z, aa.z); aa.w = fmaf(v0, x0.w, aa.w);
  }
  *(float4*)&O[(size_t)m * 4096 + c] = aa;
}

// MFMA GEMM: (20800 x 384) @ W(384 x NW), bf16x3, fp32 acc.
// A from 6 stride-64 chunks. Block = 64-row panel (one node), 4 waves,
// wave tile 32 x NW/2.
// MODE 0: sg=sigmoid(acc+b); c<64 -> rh=sg*h ; c>=64 -> u=sg.
// MODE 1: cv=tanh(acc+b); h = u*h+(1-u)*cv; DEC: fused output head.
template<int NW, int MODE, int DEC>
__global__ void __launch_bounds__(256, 4)
k_gemm(Ptr6 ch, const unsigned short* __restrict__ Wh,
       const unsigned short* __restrict__ Wl, const float* __restrict__ bias,
       float* __restrict__ hbuf, float* __restrict__ rh, float* __restrict__ ubuf,
       const float* __restrict__ Wo1, const float* __restrict__ bo1,
       const float* __restrict__ Wo2, const float* __restrict__ bo2,
       float* __restrict__ out, int qidx) {
  constexpr int CT = NW / 32;
  int row0 = blockIdx.x * 64;
  int tid = threadIdx.x;
  int lane = tid & 63, w = tid >> 6;
  int rbase = (w & 1) * 32;
  int cbase = (w >> 1) * (NW / 2);
  __shared__ unsigned short Ah[64 * 40], Al[64 * 40];
  __shared__ unsigned short Bh[NW * 40], Bl[NW * 40];
  __shared__ float hnewS[DEC ? 64 : 1][DEC ? 68 : 1];
  f32x4 acc[2][CT];
  #pragma unroll
  for (int i = 0; i < 2; i++)
    #pragma unroll
    for (int j = 0; j < CT; j++) acc[i][j] = (f32x4)0.f;

  for (int kt = 0; kt < 12; kt++) {
    int chunk = kt >> 1, kin = (kt & 1) * 32;
    const float* Ap = ch.p[chunk];
    #pragma unroll
    for (int p = 0; p < 2; p++) {
      int r = (tid >> 3) + p * 32;
      int kf = (tid & 7) * 4;
      float4 v = *(const float4*)(Ap + (size_t)(row0 + r) * 64 + kin + kf);
      unsigned short h0 = f2bf(v.x), h1 = f2bf(v.y), h2 = f2bf(v.z), h3 = f2bf(v.w);
      unsigned short l0 = f2bf(v.x - bf2f(h0)), l1 = f2bf(v.y - bf2f(h1));
      unsigned short l2 = f2bf(v.z - bf2f(h2)), l3 = f2bf(v.w - bf2f(h3));
      ushort4 hv = {h0, h1, h2, h3}, lv = {l0, l1, l2, l3};
      *(ushort4*)&Ah[r * 40 + kf] = hv;
      *(ushort4*)&Al[r * 40 + kf] = lv;
    }
    #pragma unroll
    for (int i = tid; i < NW * 4; i += 256) {
      int n = i >> 2, q = (i & 3) * 8;
      *(frag8*)&Bh[n * 40 + q] = *(const frag8*)&Wh[n * 384 + kt * 32 + q];
      *(frag8*)&Bl[n * 40 + q] = *(const frag8*)&Wl[n * 384 + kt * 32 + q];
    }
    __syncthreads();
    int rq = (lane >> 4) * 8;
    frag8 fa_h[2], fa_l[2];
    #pragma unroll
    for (int rt = 0; rt < 2; rt++) {
      int r = rbase + rt * 16 + (lane & 15);
      fa_h[rt] = *(const frag8*)&Ah[r * 40 + rq];
      fa_l[rt] = *(const frag8*)&Al[r * 40 + rq];
    }
    #pragma unroll
    for (int ct = 0; ct < CT; ct++) {
      int c = cbase + ct * 16 + (lane & 15);
      frag8 bh = *(const frag8*)&Bh[c * 40 + rq];
      frag8 bl = *(const frag8*)&Bl[c * 40 + rq];
      #pragma unroll
      for (int rt = 0; rt < 2; rt++) {
        acc[rt][ct] = __builtin_amdgcn_mfma_f32_16x16x32_bf16(fa_h[rt], bh, acc[rt][ct], 0, 0, 0);
        acc[rt][ct] = __builtin_amdgcn_mfma_f32_16x16x32_bf16(fa_l[rt], bh, acc[rt][ct], 0, 0, 0);
        acc[rt][ct] = __builtin_amdgcn_mfma_f32_16x16x32_bf16(fa_h[rt], bl, acc[rt][ct], 0, 0, 0);
      }
    }
    __syncthreads();
  }
  // epilogue: C/D layout col=lane&15, row=(lane>>4)*4+reg
  #pragma unroll
  for (int rt = 0; rt < 2; rt++)
    #pragma unroll
    for (int ct = 0; ct < CT; ct++)
      #pragma unroll
      for (int g = 0; g < 4; g++) {
        int rloc = rbase + rt * 16 + (lane >> 4) * 4 + g;
        int r = row0 + rloc;
        int c = cbase + ct * 16 + (lane & 15);
        float v = acc[rt][ct][g] + bias[c];
        if (MODE == 0) {
          float sg = 1.f / (1.f + __expf(-v));
          if (NW == 128 && c >= ND) ubuf[(size_t)r * ND + (c - ND)] = sg;
          else rh[(size_t)r * ND + c] = sg * hbuf[(size_t)r * ND + c];
        } else {
          float cv = tanhf(v);
          float uu = ubuf[(size_t)r * ND + c];
          float ho = hbuf[(size_t)r * ND + c];
          float hn = uu * ho + (1.f - uu) * cv;
          hbuf[(size_t)r * ND + c] = hn;
          if (DEC) hnewS[rloc][c] = hn;
        }
      }
  if (DEC) {
    __syncthreads();
    int r2 = tid >> 2;            // batch b = r2, node n = blockIdx.x
    int dg = (tid & 3) * 16;
    float p = 0.f;
    #pragma unroll
    for (int i = 0; i < 16; i++) {
      int d = dg + i;
      float a = bo1[d];
      #pragma unroll 8
      for (int k = 0; k < ND; k++) a = fmaf(hnewS[r2][k], Wo1[k * ND + d], a);
      a = a > 0.f ? a : 0.f;
      p = fmaf(a, Wo2[d], p);
    }
    p += __shfl_down(p, 2);
    p += __shfl_down(p, 1);
    if ((tid & 3) == 0)
      out[((size_t)r2 * NQ + qidx) * NN + blockIdx.x] = p + bo2[0];
  }
}

extern "C" void kernel_launch(void* const* d_in, const int* in_sizes, int n_in,
                              void* d_out, int out_size, void* d_ws, size_t ws_size,
                              hipStream_t stream) {
  const float* X     = (const float*)d_in[0];
  const int*   TE    = (const int*)  d_in[1];
  const float* S0    = (const float*)d_in[2];
  const float* S1    = (const float*)d_in[3];
  const float* W_te1 = (const float*)d_in[4];
  const float* b_te1 = (const float*)d_in[5];
  const float* W_te2 = (const float*)d_in[6];
  const float* b_te2 = (const float*)d_in[7];
  const float* E_se  = (const float*)d_in[8];
  const float* W_in1 = (const float*)d_in[9];
  const float* b_in1 = (const float*)d_in[10];
  const float* W_in2 = (const float*)d_in[11];
  const float* b_in2 = (const float*)d_in[12];
  const float* enc_Wg = (const float*)d_in[13];
  const float* enc_bg = (const float*)d_in[14];
  const float* enc_Wc = (const float*)d_in[15];
  const float* enc_bc = (const float*)d_in[16];
  const float* dec_Wg = (const float*)d_in[17];
  const float* dec_bg = (const float*)d_in[18];
  const float* dec_Wc = (const float*)d_in[19];
  const float* dec_bc = (const float*)d_in[20];
  const float* W_out1 = (const float*)d_in[21];
  const float* b_out1 = (const float*)d_in[22];
  const float* W_out2 = (const float*)d_in[23];
  const float* b_out2 = (const float*)d_in[24];
  float* out = (float*)d_out;
  float* ws = (float*)d_ws;

  // workspace layout (floats); ~177 MB
  float* te  = ws;                    // 98304
  float* h   = te + 98304;
  float* rh  = h + TSZ;
  float* u   = rh + TSZ;
  float* SX0 = u + TSZ;
  float* SX1 = SX0 + TSZ;
  float* SH0 = SX1 + TSZ;
  float* SH1 = SH0 + TSZ;
  float* SR0 = SH1 + TSZ;
  float* SR1 = SR0 + TSZ;
  float* Xe  = SR1 + TSZ;             // 24*TSZ
  float* csrV = Xe + 24 * (size_t)TSZ;
  int*   csrI = (int*)(csrV + 2 * NN * CAP);
  int*   csrC = csrI + 2 * NN * CAP;  // 650, pad 1024
  unsigned short* wbuf = (unsigned short*)(csrC + 1024);
  unsigned short* egWh = wbuf;
  unsigned short* egWl = egWh + 49152;
  unsigned short* dgWh = egWl + 49152;
  unsigned short* dgWl = dgWh + 49152;
  unsigned short* ecWh = dgWl + 49152;
  unsigned short* ecWl = ecWh + 24576;
  unsigned short* dcWh = ecWl + 24576;
  unsigned short* dcWl = dcWh + 24576;

  k_te<<<NB * NT, ND, 0, stream>>>(TE, W_te1, b_te1, W_te2, b_te2, te);
  k_zero<<<(TSZ + 255) / 256, 256, 0, stream>>>(h, TSZ);
  k_csr<<<dim3(NN, 2), 64, 0, stream>>>(S0, S1, csrC, csrI, csrV);
  k_convW<<<384, 128, 0, stream>>>(enc_Wg, egWh, egWl, 128);
  k_convW<<<384, 128, 0, stream>>>(dec_Wg, dgWh, dgWl, 128);
  k_convW<<<384,  64, 0, stream>>>(enc_Wc, ecWh, ecWl, 64);
  k_convW<<<384,  64, 0, stream>>>(dec_Wc, dcWh, dcWl, 64);
  k_xe<<<dim3(NR / 4, NT), 256, 0, stream>>>(X, te, E_se, W_in1, b_in1, W_in2, b_in2, Xe);

  for (int t = 0; t < NT; t++) {
    int enc = (t < NP) ? 1 : 0;
    const unsigned short* Wgh = enc ? egWh : dgWh;
    const unsigned short* Wgl = enc ? egWl : dgWl;
    const unsigned short* Wch = enc ? ecWh : dcWh;
    const unsigned short* Wcl = enc ? ecWl : dcWl;
    const float* bg = enc ? enc_bg : dec_bg;
    const float* bc = enc ? enc_bc : dec_bc;
    const float* Xe_t = Xe + (size_t)t * TSZ;

    // K-chunk order matches W rows: [x, h, S0x, S0h, S1x, S1h]
    Ptr6 gateCh{{Xe_t, h, SX0, SH0, SX1, SH1}};
    Ptr6 candCh{{Xe_t, rh, SX0, SR0, SX1, SR1}};

    k_g2<<<dim3(4, NN, 2), 256, 0, stream>>>(Xe_t, h, csrC, csrI, csrV,
                                             SX0, SH0, SX1, SH1);
    k_gemm<128, 0, 0><<<NN, 256, 0, stream>>>(gateCh, Wgh, Wgl, bg, h, rh, u,
                                              nullptr, nullptr, nullptr, nullptr,
                                              nullptr, 0);
    k_g1<<<dim3(4, NN, 2), 256, 0, stream>>>(rh, csrC, csrI, csrV, SR0, SR1);
    if (enc)
      k_gemm<64, 1, 0><<<NN, 256, 0, stream>>>(candCh, Wch, Wcl, bc, h, rh, u,
                                               nullptr, nullptr, nullptr, nullptr,
                                               nullptr, 0);
    else
      k_gemm<64, 1, 1><<<NN, 256, 0, stream>>>(candCh, Wch, Wcl, bc, h, rh, u,
                                               W_out1, b_out1, W_out2, b_out2,
                                               out, t - NP);
  }
}

// Round 6
// 2498.614 us; speedup vs baseline: 1.4446x; 1.1451x over previous
//
#include <hip/hip_runtime.h>
#include <math.h>

#define NB 64      // batch
#define NP 12      // encoder steps
#define NQ 12      // decoder steps
#define NT 24      // P+Q
#define NN 325     // nodes
#define ND 64      // units
#define NR 20800   // NN*NB rows
#define CAP 64     // max nnz per S row (mean ~20.5, max ~40)
#define TSZ 1331200  // NR*ND, one time-slice

typedef __attribute__((ext_vector_type(8))) short frag8;
typedef __attribute__((ext_vector_type(4))) float f32x4;

struct Ptr6 { const float* p[6]; };

__device__ inline unsigned short f2bf(float f) {
  unsigned u = __builtin_bit_cast(unsigned, f);
  unsigned r = u + 0x7FFFu + ((u >> 16) & 1u);
  return (unsigned short)(r >> 16);
}
__device__ inline float bf2f(unsigned short h) {
  unsigned u = ((unsigned)h) << 16;
  return __builtin_bit_cast(float, u);
}

__global__ void k_te(const int* __restrict__ TE, const float* __restrict__ W1,
                     const float* __restrict__ b1, const float* __restrict__ W2,
                     const float* __restrict__ b2, float* __restrict__ te) {
  int row = blockIdx.x;            // b*24+t
  int d = threadIdx.x;
  __shared__ float s[ND];
  int wd = TE[row * 2 + 0], td = TE[row * 2 + 1];
  float v = W1[wd * ND + d] + W1[(7 + td) * ND + d] + b1[d];
  s[d] = v > 0.f ? v : 0.f;
  __syncthreads();
  float acc = b2[d];
  #pragma unroll 8
  for (int k = 0; k < ND; k++) acc = fmaf(s[k], W2[k * ND + d], acc);
  te[row * ND + d] = acc;
}

__global__ void k_zero(float* __restrict__ p, int n) {
  int i = blockIdx.x * 256 + threadIdx.x;
  if (i < n) p[i] = 0.f;
}

// W (384 x nw) fp32 -> k-major bf16 hi/lo: Wh/Wl[n*384 + k]
__global__ void k_convW(const float* __restrict__ W, unsigned short* __restrict__ Wh,
                        unsigned short* __restrict__ Wl, int nw) {
  int k = blockIdx.x;              // 384
  int n = threadIdx.x;             // nw
  float w = W[k * nw + n];
  unsigned short h = f2bf(w);
  Wh[n * 384 + k] = h;
  Wl[n * 384 + k] = f2bf(w - bf2f(h));
}

// CSR build for S0/S1
__global__ void k_csr(const float* __restrict__ S0g, const float* __restrict__ S1g,
                      int* __restrict__ cnt, int* __restrict__ idx,
                      float* __restrict__ val) {
  int m = blockIdx.x, z = blockIdx.y;
  const float* S = z ? S1g : S0g;
  int lane = threadIdx.x;
  int c = 0;
  for (int k0 = 0; k0 < NN; k0 += 64) {
    int k = k0 + lane;
    float v = (k < NN) ? S[m * NN + k] : 0.f;
    bool p = (v != 0.f);
    unsigned long long mask = __ballot(p);
    int pos = c + __popcll(mask & ((1ull << lane) - 1ull));
    if (p) {
      idx[(z * NN + m) * CAP + pos] = k;
      val[(z * NN + m) * CAP + pos] = v;
    }
    c += __popcll(mask);
  }
  if (lane == 0) cnt[z * NN + m] = c;
}

// Precompute Xe[t][row][d] for all steps. 16 rows/block, 4 d per thread.
__global__ void k_xe(const float* __restrict__ X, const float* __restrict__ te,
                     const float* __restrict__ E_se, const float* __restrict__ Wi1,
                     const float* __restrict__ bi1, const float* __restrict__ Wi2,
                     const float* __restrict__ bi2, float* __restrict__ Xe) {
  int t = blockIdx.y;
  int r = threadIdx.x >> 4;               // local row 0..15
  int row = blockIdx.x * 16 + r;
  int n = row >> 6, b = row & 63;
  int dq = (threadIdx.x & 15) * 4;        // 4 output dims
  float4 tev = *(const float4*)&te[(b * NT + t) * ND + dq];
  float4 ev  = *(const float4*)&E_se[n * ND + dq];
  float4 acc;
  if (t < NP) {
    __shared__ float s[16][65];           // +1 pad: kill 16-way bank conflict
    float x = X[(b * NP + t) * NN + n];
    float4 w1 = *(const float4*)&Wi1[dq];
    float4 b1 = *(const float4*)&bi1[dq];
    s[r][dq + 0] = fmaxf(fmaf(x, w1.x, b1.x), 0.f);
    s[r][dq + 1] = fmaxf(fmaf(x, w1.y, b1.y), 0.f);
    s[r][dq + 2] = fmaxf(fmaf(x, w1.z, b1.z), 0.f);
    s[r][dq + 3] = fmaxf(fmaf(x, w1.w, b1.w), 0.f);
    __syncthreads();
    acc = *(const float4*)&bi2[dq];
    #pragma unroll 8
    for (int k = 0; k < ND; k++) {
      float sv = s[r][k];
      float4 w2 = *(const float4*)&Wi2[k * ND + dq];
      acc.x = fmaf(sv, w2.x, acc.x); acc.y = fmaf(sv, w2.y, acc.y);
      acc.z = fmaf(sv, w2.z, acc.z); acc.w = fmaf(sv, w2.w, acc.w);
    }
    acc.x += tev.x + ev.x; acc.y += tev.y + ev.y;
    acc.z += tev.z + ev.z; acc.w += tev.w + ev.w;
  } else {
    acc = make_float4(tev.x + ev.x, tev.y + ev.y, tev.z + ev.z, tev.w + ev.w);
  }
  *(float4*)&Xe[(size_t)t * TSZ + (size_t)row * ND + dq] = acc;
}

// Dual gather, XCD-local: blockIdx.x = 512-col chunk (-> XCD via %8 round-robin).
// Waves 0-1: support 0; waves 2-3: support 1.
__global__ void k_g2(const float* __restrict__ A, const float* __restrict__ Bsrc,
                     const int* __restrict__ cnt, const int* __restrict__ idx,
                     const float* __restrict__ val,
                     float* __restrict__ OA0, float* __restrict__ OB0,
                     float* __restrict__ OA1, float* __restrict__ OB1) {
  int xc = blockIdx.x, m = blockIdx.y;
  int tid = threadIdx.x;
  int z = tid >> 7, lid = tid & 127;
  int c = xc * 512 + lid * 4;
  __shared__ int sI[2][CAP];
  __shared__ float sV[2][CAP];
  __shared__ int scnt[2];
  if (tid < 2) scnt[tid] = cnt[tid * NN + m];
  __syncthreads();
  int n = scnt[z];
  if (lid < n) {
    sI[z][lid] = idx[(z * NN + m) * CAP + lid];
    sV[z][lid] = val[(z * NN + m) * CAP + lid];
  }
  __syncthreads();
  float4 aa = make_float4(0.f, 0.f, 0.f, 0.f);
  float4 ab = make_float4(0.f, 0.f, 0.f, 0.f);
  for (int j = 0; j < n; j++) {
    float v = sV[z][j];
    size_t ka = (size_t)sI[z][j] * 4096 + c;
    float4 x = *(const float4*)&A[ka];
    float4 y = *(const float4*)&Bsrc[ka];
    aa.x = fmaf(v, x.x, aa.x); aa.y = fmaf(v, x.y, aa.y);
    aa.z = fmaf(v, x.z, aa.z); aa.w = fmaf(v, x.w, aa.w);
    ab.x = fmaf(v, y.x, ab.x); ab.y = fmaf(v, y.y, ab.y);
    ab.z = fmaf(v, y.z, ab.z); ab.w = fmaf(v, y.w, ab.w);
  }
  float* OA = z ? OA1 : OA0;
  float* OB = z ? OB1 : OB0;
  *(float4*)&OA[(size_t)m * 4096 + c] = aa;
  *(float4*)&OB[(size_t)m * 4096 + c] = ab;
}

// Single gather (rh), same XCD-local scheme.
__global__ void k_g1(const float* __restrict__ A, const int* __restrict__ cnt,
                     const int* __restrict__ idx, const float* __restrict__ val,
                     float* __restrict__ O0, float* __restrict__ O1) {
  int xc = blockIdx.x, m = blockIdx.y;
  int tid = threadIdx.x;
  int z = tid >> 7, lid = tid & 127;
  int c = xc * 512 + lid * 4;
  __shared__ int sI[2][CAP];
  __shared__ float sV[2][CAP];
  __shared__ int scnt[2];
  if (tid < 2) scnt[tid] = cnt[tid * NN + m];
  __syncthreads();
  int n = scnt[z];
  if (lid < n) {
    sI[z][lid] = idx[(z * NN + m) * CAP + lid];
    sV[z][lid] = val[(z * NN + m) * CAP + lid];
  }
  __syncthreads();
  float4 aa = make_float4(0.f, 0.f, 0.f, 0.f);
  for (int j = 0; j < n; j++) {
    float v = sV[z][j];
    float4 x = *(const float4*)&A[(size_t)sI[z][j] * 4096 + c];
    aa.x = fmaf(v, x.x, aa.x); aa.y = fmaf(v, x.y, aa.y);
    aa.z = fmaf(v, x.z, aa.z); aa.w = fmaf(v, x.w, aa.w);
  }
  float* O = z ? O1 : O0;
  *(float4*)&O[(size_t)m * 4096 + c] = aa;
}

// MFMA GEMM: (20800 x 384) @ W(384 x NW), bf16x3, fp32 acc. 32-row panels
// (650 blocks for load balance). 4 waves, wave tile 16 x NW/2.
// MODE 0: sg=sigmoid(acc+b); c<64 -> rh=sg*h ; c>=64 -> u=sg.
// MODE 1: cv=tanh(acc+b); h = u*h+(1-u)*cv; DEC adds fused output head.
template<int NW, int MODE, int DEC>
__global__ void __launch_bounds__(256, 4)
k_gemm(Ptr6 ch, const unsigned short* __restrict__ Wh,
       const unsigned short* __restrict__ Wl, const float* __restrict__ bias,
       float* __restrict__ hbuf, float* __restrict__ rh, float* __restrict__ ubuf,
       const float* __restrict__ Wo1, const float* __restrict__ bo1,
       const float* __restrict__ Wo2, const float* __restrict__ bo2,
       float* __restrict__ out, int qidx) {
  constexpr int CT = NW / 32;
  int row0 = blockIdx.x * 32;
  int tid = threadIdx.x;
  int lane = tid & 63, w = tid >> 6;
  int rbase = (w & 1) * 16;
  int cbase = (w >> 1) * (NW / 2);
  __shared__ unsigned short Ah[32 * 40], Al[32 * 40];
  __shared__ unsigned short Bh[NW * 40], Bl[NW * 40];
  __shared__ float hnewS[DEC ? 32 : 1][DEC ? 68 : 1];
  f32x4 acc[CT];
  #pragma unroll
  for (int j = 0; j < CT; j++) acc[j] = (f32x4)0.f;

  for (int kt = 0; kt < 12; kt++) {
    int chunk = kt >> 1, kin = (kt & 1) * 32;
    const float* Ap = ch.p[chunk];
    {
      int r = tid >> 3;
      int kf = (tid & 7) * 4;
      float4 v = *(const float4*)(Ap + (size_t)(row0 + r) * 64 + kin + kf);
      unsigned short h0 = f2bf(v.x), h1 = f2bf(v.y), h2 = f2bf(v.z), h3 = f2bf(v.w);
      unsigned short l0 = f2bf(v.x - bf2f(h0)), l1 = f2bf(v.y - bf2f(h1));
      unsigned short l2 = f2bf(v.z - bf2f(h2)), l3 = f2bf(v.w - bf2f(h3));
      ushort4 hv = {h0, h1, h2, h3}, lv = {l0, l1, l2, l3};
      *(ushort4*)&Ah[r * 40 + kf] = hv;
      *(ushort4*)&Al[r * 40 + kf] = lv;
    }
    #pragma unroll
    for (int i = tid; i < NW * 4; i += 256) {
      int n = i >> 2, q = (i & 3) * 8;
      *(frag8*)&Bh[n * 40 + q] = *(const frag8*)&Wh[n * 384 + kt * 32 + q];
      *(frag8*)&Bl[n * 40 + q] = *(const frag8*)&Wl[n * 384 + kt * 32 + q];
    }
    __syncthreads();
    int rq = (lane >> 4) * 8;
    int arow = rbase + (lane & 15);
    frag8 fa_h = *(const frag8*)&Ah[arow * 40 + rq];
    frag8 fa_l = *(const frag8*)&Al[arow * 40 + rq];
    #pragma unroll
    for (int ct = 0; ct < CT; ct++) {
      int c = cbase + ct * 16 + (lane & 15);
      frag8 bh = *(const frag8*)&Bh[c * 40 + rq];
      frag8 bl = *(const frag8*)&Bl[c * 40 + rq];
      acc[ct] = __builtin_amdgcn_mfma_f32_16x16x32_bf16(fa_h, bh, acc[ct], 0, 0, 0);
      acc[ct] = __builtin_amdgcn_mfma_f32_16x16x32_bf16(fa_l, bh, acc[ct], 0, 0, 0);
      acc[ct] = __builtin_amdgcn_mfma_f32_16x16x32_bf16(fa_h, bl, acc[ct], 0, 0, 0);
    }
    __syncthreads();
  }
  // epilogue: C/D layout col=lane&15, row=(lane>>4)*4+reg
  #pragma unroll
  for (int ct = 0; ct < CT; ct++)
    #pragma unroll
    for (int g = 0; g < 4; g++) {
      int rloc = rbase + (lane >> 4) * 4 + g;
      int r = row0 + rloc;
      int c = cbase + ct * 16 + (lane & 15);
      float v = acc[ct][g] + bias[c];
      if (MODE == 0) {
        float sg = 1.f / (1.f + __expf(-v));
        if (NW == 128 && c >= ND) ubuf[(size_t)r * ND + (c - ND)] = sg;
        else rh[(size_t)r * ND + c] = sg * hbuf[(size_t)r * ND + c];
      } else {
        float cv = tanhf(v);
        float uu = ubuf[(size_t)r * ND + c];
        float ho = hbuf[(size_t)r * ND + c];
        float hn = uu * ho + (1.f - uu) * cv;
        hbuf[(size_t)r * ND + c] = hn;
        if (DEC) hnewS[rloc][c] = hn;
      }
    }
  if (DEC) {
    __syncthreads();
    if (tid < 128) {
      int r2 = tid >> 2;                 // 0..31
      int dg = (tid & 3) * 16;
      int node = blockIdx.x >> 1;
      int b = (blockIdx.x & 1) * 32 + r2;
      float p = 0.f;
      #pragma unroll
      for (int i = 0; i < 16; i++) {
        int d = dg + i;
        float a = bo1[d];
        #pragma unroll 8
        for (int k = 0; k < ND; k++) a = fmaf(hnewS[r2][k], Wo1[k * ND + d], a);
        a = a > 0.f ? a : 0.f;
        p = fmaf(a, Wo2[d], p);
      }
      p += __shfl_down(p, 2);
      p += __shfl_down(p, 1);
      if ((tid & 3) == 0)
        out[((size_t)b * NQ + qidx) * NN + node] = p + bo2[0];
    }
  }
}

extern "C" void kernel_launch(void* const* d_in, const int* in_sizes, int n_in,
                              void* d_out, int out_size, void* d_ws, size_t ws_size,
                              hipStream_t stream) {
  const float* X     = (const float*)d_in[0];
  const int*   TE    = (const int*)  d_in[1];
  const float* S0    = (const float*)d_in[2];
  const float* S1    = (const float*)d_in[3];
  const float* W_te1 = (const float*)d_in[4];
  const float* b_te1 = (const float*)d_in[5];
  const float* W_te2 = (const float*)d_in[6];
  const float* b_te2 = (const float*)d_in[7];
  const float* E_se  = (const float*)d_in[8];
  const float* W_in1 = (const float*)d_in[9];
  const float* b_in1 = (const float*)d_in[10];
  const float* W_in2 = (const float*)d_in[11];
  const float* b_in2 = (const float*)d_in[12];
  const float* enc_Wg = (const float*)d_in[13];
  const float* enc_bg = (const float*)d_in[14];
  const float* enc_Wc = (const float*)d_in[15];
  const float* enc_bc = (const float*)d_in[16];
  const float* dec_Wg = (const float*)d_in[17];
  const float* dec_bg = (const float*)d_in[18];
  const float* dec_Wc = (const float*)d_in[19];
  const float* dec_bc = (const float*)d_in[20];
  const float* W_out1 = (const float*)d_in[21];
  const float* b_out1 = (const float*)d_in[22];
  const float* W_out2 = (const float*)d_in[23];
  const float* b_out2 = (const float*)d_in[24];
  float* out = (float*)d_out;
  float* ws = (float*)d_ws;

  // workspace layout (floats); ~177 MB
  float* te  = ws;                    // 98304
  float* h   = te + 98304;
  float* rh  = h + TSZ;
  float* u   = rh + TSZ;
  float* SX0 = u + TSZ;
  float* SX1 = SX0 + TSZ;
  float* SH0 = SX1 + TSZ;
  float* SH1 = SH0 + TSZ;
  float* SR0 = SH1 + TSZ;
  float* SR1 = SR0 + TSZ;
  float* Xe  = SR1 + TSZ;             // 24*TSZ
  float* csrV = Xe + 24 * (size_t)TSZ;
  int*   csrI = (int*)(csrV + 2 * NN * CAP);
  int*   csrC = csrI + 2 * NN * CAP;  // 650, pad 1024
  unsigned short* wbuf = (unsigned short*)(csrC + 1024);
  unsigned short* egWh = wbuf;
  unsigned short* egWl = egWh + 49152;
  unsigned short* dgWh = egWl + 49152;
  unsigned short* dgWl = dgWh + 49152;
  unsigned short* ecWh = dgWl + 49152;
  unsigned short* ecWl = ecWh + 24576;
  unsigned short* dcWh = ecWl + 24576;
  unsigned short* dcWl = dcWh + 24576;

  k_te<<<NB * NT, ND, 0, stream>>>(TE, W_te1, b_te1, W_te2, b_te2, te);
  k_zero<<<(TSZ + 255) / 256, 256, 0, stream>>>(h, TSZ);
  k_csr<<<dim3(NN, 2), 64, 0, stream>>>(S0, S1, csrC, csrI, csrV);
  k_convW<<<384, 128, 0, stream>>>(enc_Wg, egWh, egWl, 128);
  k_convW<<<384, 128, 0, stream>>>(dec_Wg, dgWh, dgWl, 128);
  k_convW<<<384,  64, 0, stream>>>(enc_Wc, ecWh, ecWl, 64);
  k_convW<<<384,  64, 0, stream>>>(dec_Wc, dcWh, dcWl, 64);
  k_xe<<<dim3(NR / 16, NT), 256, 0, stream>>>(X, te, E_se, W_in1, b_in1, W_in2, b_in2, Xe);

  for (int t = 0; t < NT; t++) {
    int enc = (t < NP) ? 1 : 0;
    const unsigned short* Wgh = enc ? egWh : dgWh;
    const unsigned short* Wgl = enc ? egWl : dgWl;
    const unsigned short* Wch = enc ? ecWh : dcWh;
    const unsigned short* Wcl = enc ? ecWl : dcWl;
    const float* bg = enc ? enc_bg : dec_bg;
    const float* bc = enc ? enc_bc : dec_bc;
    const float* Xe_t = Xe + (size_t)t * TSZ;

    // K-chunk order matches W rows: [x, h, S0x, S0h, S1x, S1h]
    Ptr6 gateCh{{Xe_t, h, SX0, SH0, SX1, SH1}};
    Ptr6 candCh{{Xe_t, rh, SX0, SR0, SX1, SR1}};

    k_g2<<<dim3(8, NN), 256, 0, stream>>>(Xe_t, h, csrC, csrI, csrV,
                                          SX0, SH0, SX1, SH1);
    k_gemm<128, 0, 0><<<NN * 2, 256, 0, stream>>>(gateCh, Wgh, Wgl, bg, h, rh, u,
                                                  nullptr, nullptr, nullptr, nullptr,
                                                  nullptr, 0);
    k_g1<<<dim3(8, NN), 256, 0, stream>>>(rh, csrC, csrI, csrV, SR0, SR1);
    if (enc)
      k_gemm<64, 1, 0><<<NN * 2, 256, 0, stream>>>(candCh, Wch, Wcl, bc, h, rh, u,
                                                   nullptr, nullptr, nullptr, nullptr,
                                                   nullptr, 0);
    else
      k_gemm<64, 1, 1><<<NN * 2, 256, 0, stream>>>(candCh, Wch, Wcl, bc, h, rh, u,
                                                   W_out1, b_out1, W_out2, b_out2,
                                                   out, t - NP);
  }
}